// Round 1
// baseline (517.223 us; speedup 1.0000x reference)
//
#include <hip/hip_runtime.h>
#include <hip/hip_bf16.h>
#include <hip/hip_fp16.h>

#define B_ 2
#define T_ 2048
#define DM 1024
#define H_ 16
#define HD_ 64

typedef __attribute__((ext_vector_type(8))) short bf16x8v;
typedef __attribute__((ext_vector_type(4))) short short4v;
typedef __attribute__((ext_vector_type(4))) float f32x4;

__device__ __forceinline__ short f2bf(float f){
  unsigned u = __builtin_bit_cast(unsigned, f);
  u += 0x7fffu + ((u >> 16) & 1u);
  return (short)(u >> 16);
}
__device__ __forceinline__ float bf2f(short s){
  unsigned u = ((unsigned)(unsigned short)s) << 16;
  return __builtin_bit_cast(float, u);
}
__device__ __forceinline__ short f2h(float f){
  return __builtin_bit_cast(short, __float2half(f));
}
__device__ __forceinline__ float h2f(short s){
  return __half2float(__builtin_bit_cast(__half, s));
}

#define GLOAD_LDS16(g, l) \
  __builtin_amdgcn_global_load_lds((const __attribute__((address_space(1))) unsigned int*)(g), \
                                   (__attribute__((address_space(3))) unsigned int*)(l), 16, 0, 0)

#define MFMA16(a, b, c) __builtin_amdgcn_mfma_f32_16x16x32_bf16((a), (b), (c), 0, 0, 0)

// ---------------------------------------------------------------------------
// fp32 -> bf16 conversion for 3 activations (4M elems) + 4 weights (1M elems)
// ---------------------------------------------------------------------------
__global__ __launch_bounds__(256) void conv_kernel(
    const float* __restrict__ s0, const float* __restrict__ s1, const float* __restrict__ s2,
    const float* __restrict__ s3, const float* __restrict__ s4, const float* __restrict__ s5,
    const float* __restrict__ s6,
    short* __restrict__ d0, short* __restrict__ d1, short* __restrict__ d2,
    short* __restrict__ d3, short* __restrict__ d4, short* __restrict__ d5,
    short* __restrict__ d6)
{
  int y = blockIdx.y;
  const float* s; short* d; int n;
  switch (y) {
    case 0: s = s0; d = d0; n = B_*T_*DM; break;
    case 1: s = s1; d = d1; n = B_*T_*DM; break;
    case 2: s = s2; d = d2; n = B_*T_*DM; break;
    case 3: s = s3; d = d3; n = DM*DM;   break;
    case 4: s = s4; d = d4; n = DM*DM;   break;
    case 5: s = s5; d = d5; n = DM*DM;   break;
    default: s = s6; d = d6; n = DM*DM;  break;
  }
  int i = (blockIdx.x * 256 + threadIdx.x) * 4;
  if (i >= n) return;
  float4 f = *(const float4*)(s + i);
  short4v o;
  o.x = f2bf(f.x); o.y = f2bf(f.y); o.z = f2bf(f.z); o.w = f2bf(f.w);
  *(short4v*)(d + i) = o;
}

// ---------------------------------------------------------------------------
// Projection GEMM: C = X(4096x1024) * W^T(1024x1024), bf16 MFMA, 128x128 tile.
// z=0: Q (scaled 1/8) -> [b,h,t,hd]; z=1: K -> [b,h,t,hd]; z=2: V -> [b,h,hd,t]
// ---------------------------------------------------------------------------
__global__ __launch_bounds__(256) void proj_gemm(
    const short* __restrict__ xq, const short* __restrict__ xk, const short* __restrict__ xv,
    const short* __restrict__ wq, const short* __restrict__ wk, const short* __restrict__ wv,
    short* __restrict__ qo, short* __restrict__ ko, short* __restrict__ vto)
{
  __shared__ short As[128 * 32];
  __shared__ short Bs[128 * 32];
  const int z = blockIdx.z;
  const short* A  = (z == 0) ? xq : (z == 1) ? xk : xv;
  const short* Bw = (z == 0) ? wq : (z == 1) ? wk : wv;
  const int m0 = blockIdx.x * 128;
  const int n0 = blockIdx.y * 128;
  const int tid = threadIdx.x;
  const int w = tid >> 6, l = tid & 63;
  const int wr = w >> 1, wc = w & 1;
  const int fr = l & 15, kq8 = (l >> 4) * 8;
  const int srow = tid >> 2, scol = (tid & 3) * 8;

  f32x4 acc[4][4] = {};

  for (int k0 = 0; k0 < DM; k0 += 32) {
    __syncthreads();
    GLOAD_LDS16(A  + (size_t)(m0 + srow) * DM + k0 + scol,      (char*)As + tid * 16);
    GLOAD_LDS16(A  + (size_t)(m0 + 64 + srow) * DM + k0 + scol, (char*)As + 4096 + tid * 16);
    GLOAD_LDS16(Bw + (size_t)(n0 + srow) * DM + k0 + scol,      (char*)Bs + tid * 16);
    GLOAD_LDS16(Bw + (size_t)(n0 + 64 + srow) * DM + k0 + scol, (char*)Bs + 4096 + tid * 16);
    __syncthreads();
    bf16x8v a[4], b[4];
#pragma unroll
    for (int i = 0; i < 4; i++) a[i] = *(const bf16x8v*)&As[(wr * 64 + i * 16 + fr) * 32 + kq8];
#pragma unroll
    for (int j = 0; j < 4; j++) b[j] = *(const bf16x8v*)&Bs[(wc * 64 + j * 16 + fr) * 32 + kq8];
#pragma unroll
    for (int i = 0; i < 4; i++)
#pragma unroll
      for (int j = 0; j < 4; j++)
        acc[i][j] = MFMA16(a[i], b[j], acc[i][j]);
  }

  const float scale = (z == 0) ? 0.125f : 1.0f;
  short* dst01 = (z == 0) ? qo : ko;
#pragma unroll
  for (int i = 0; i < 4; i++) {
#pragma unroll
    for (int j = 0; j < 4; j++) {
#pragma unroll
      for (int r = 0; r < 4; r++) {
        int row = m0 + wr * 64 + i * 16 + (l >> 4) * 4 + r;
        int col = n0 + wc * 64 + j * 16 + fr;
        int bb = row >> 11, tt = row & (T_ - 1);
        int hh = col >> 6,  hd = col & (HD_ - 1);
        short v = f2bf(acc[i][j][r] * scale);
        if (z == 2)
          vto[(((size_t)bb * H_ + hh) * HD_ + hd) * T_ + tt] = v;
        else
          dst01[(((size_t)bb * H_ + hh) * T_ + tt) * HD_ + hd] = v;
      }
    }
  }
}

// ---------------------------------------------------------------------------
// Column sums of V (for fully-masked rows): vs[bh*64+hd] = sum_t V[bh][t][hd]
// ---------------------------------------------------------------------------
__global__ __launch_bounds__(256) void vsum_kernel(const short* __restrict__ vt,
                                                   float* __restrict__ vs)
{
  __shared__ float red[256];
  int bh = blockIdx.x;
  int tid = threadIdx.x;
  int hd = tid & 63, part = tid >> 6;
  const short* src = vt + ((size_t)bh * HD_ + hd) * T_ + part * 512;
  float s = 0.f;
  for (int i = 0; i < 512; i += 4) {
    short4v v = *(const short4v*)(src + i);
    s += bf2f(v.x) + bf2f(v.y) + bf2f(v.z) + bf2f(v.w);
  }
  red[tid] = s;
  __syncthreads();
  if (part == 0)
    vs[(size_t)bh * HD_ + hd] = red[hd] + red[64 + hd] + red[128 + hd] + red[192 + hd];
}

// ---------------------------------------------------------------------------
// Attention: one WG per (head, 16-q-row tile), both batches fused (shared bias).
// Scores kept as fp16 in XOR-swizzled LDS; softmax; attn written fp32; P.V MFMA.
// ---------------------------------------------------------------------------
__global__ __launch_bounds__(512) void attn_kernel(
    const short* __restrict__ qw, const short* __restrict__ kw, const short* __restrict__ vt,
    const float* __restrict__ bias, const int* __restrict__ mask,
    const int* __restrict__ causal_p, const float* __restrict__ vsum,
    float* __restrict__ attn_out, short* __restrict__ outh)
{
  __shared__ short s_lds[32 * 2048];          // 128 KB: fp16 scores, then bf16 p
  __shared__ unsigned char mk_lds[2 * T_];
  __shared__ float m_lds[32], l_lds[32];

  const int h  = blockIdx.y;
  const int q0 = blockIdx.x * 16;
  const int tid = threadIdx.x;
  const int w = tid >> 6, l = tid & 63;
  const int causal = *causal_p;
  const int L = causal ? (q0 + 16) : T_;
  const int Lpad = (L + 31) & ~31;
  const int fr = l & 15, kq8 = (l >> 4) * 8;

  for (int i = tid; i < 2 * T_; i += 512)
    mk_lds[i] = (unsigned char)(mask[i] != 0);
  __syncthreads();

  // ---- phase 1: scores = (Q/8)K^T + bias, masked, -> LDS fp16 (swizzled) ----
  {
    bf16x8v qf[2][2];
#pragma unroll
    for (int b = 0; b < 2; b++)
#pragma unroll
      for (int ks = 0; ks < 2; ks++)
        qf[b][ks] = *(const bf16x8v*)&qw[(((size_t)b * H_ + h) * T_ + q0 + fr) * HD_ + ks * 32 + kq8];

    for (int nt = 0; nt < 16; ++nt) {
      int k0 = (nt * 8 + w) * 16;            // interleave tiles across waves
      if (k0 >= L) break;
      f32x4 acc0 = {0.f, 0.f, 0.f, 0.f}, acc1 = {0.f, 0.f, 0.f, 0.f};
      {
        const short* kb0 = &kw[(((size_t)0 * H_ + h) * T_ + k0 + fr) * HD_ + kq8];
        acc0 = MFMA16(qf[0][0], *(const bf16x8v*)kb0, acc0);
        acc0 = MFMA16(qf[0][1], *(const bf16x8v*)(kb0 + 32), acc0);
        const short* kb1 = &kw[(((size_t)1 * H_ + h) * T_ + k0 + fr) * HD_ + kq8];
        acc1 = MFMA16(qf[1][0], *(const bf16x8v*)kb1, acc1);
        acc1 = MFMA16(qf[1][1], *(const bf16x8v*)(kb1 + 32), acc1);
      }
      int colg = k0 + fr;
      const float* bp = bias + ((size_t)h * T_ + q0 + (l >> 4) * 4) * T_ + colg;
      unsigned char mk0 = mk_lds[colg], mk1 = mk_lds[T_ + colg];
#pragma unroll
      for (int r = 0; r < 4; r++) {
        int qrel = (l >> 4) * 4 + r;
        float bi = bp[r * T_];
        bool cok = (!causal) || (colg <= q0 + qrel);
        float s0 = (mk0 && cok) ? (acc0[r] + bi) : -1e9f;
        float s1 = (mk1 && cok) ? (acc1[r] + bi) : -1e9f;
        int row0 = qrel, row1 = 16 + qrel;
        *(short*)((char*)s_lds + ((row0 * 4096 + colg * 2) ^ ((row0 & 7) << 4))) = f2h(s0);
        *(short*)((char*)s_lds + ((row1 * 4096 + colg * 2) ^ ((row1 & 7) << 4))) = f2h(s1);
      }
    }
  }
  __syncthreads();

  // ---- phase 2: per-row max and sum(exp) over [0,L) ----
  {
    int row = tid >> 4, j = tid & 15;
    float mx = -3e38f;
    for (int c = j * 8; c < L; c += 128) {
      int byte = (row * 4096 + c * 2) ^ ((row & 7) << 4);
      bf16x8v v = *(const bf16x8v*)((char*)s_lds + byte);
#pragma unroll
      for (int i = 0; i < 8; i++) mx = fmaxf(mx, h2f(v[i]));
    }
#pragma unroll
    for (int off = 1; off < 16; off <<= 1) mx = fmaxf(mx, __shfl_xor(mx, off));
    float sm = 0.f;
    for (int c = j * 8; c < L; c += 128) {
      int byte = (row * 4096 + c * 2) ^ ((row & 7) << 4);
      bf16x8v v = *(const bf16x8v*)((char*)s_lds + byte);
#pragma unroll
      for (int i = 0; i < 8; i++) sm += __expf(h2f(v[i]) - mx);
    }
#pragma unroll
    for (int off = 1; off < 16; off <<= 1) sm += __shfl_xor(sm, off);
    if (j == 0) { m_lds[row] = mx; l_lds[row] = sm; }
  }
  __syncthreads();

  // ---- phase 3a: p = exp(s-m)/l; write attn fp32 to global; p (bf16) -> LDS ----
  {
    int row = tid >> 4, j = tid & 15;
    int b = row >> 4, qg = q0 + (row & 15);
    float mx = m_lds[row];
    bool fullmask = (mx <= -0.5e9f);
    float inv = fullmask ? 0.f : (1.0f / l_lds[row]);
    float fillv = fullmask ? (1.0f / (float)T_) : 0.f;
    float* arow = attn_out + (((size_t)b * H_ + h) * T_ + qg) * T_;
    for (int c = j * 8; c < Lpad; c += 128) {
      int byte = (row * 4096 + c * 2) ^ ((row & 7) << 4);
      if (c < L) {
        bf16x8v v = *(const bf16x8v*)((char*)s_lds + byte);
        float p[8];
#pragma unroll
        for (int i = 0; i < 8; i++)
          p[i] = fullmask ? 0.f : __expf(h2f(v[i]) - mx) * inv;
        float4 o0 = make_float4(fullmask ? fillv : p[0], fullmask ? fillv : p[1],
                                fullmask ? fillv : p[2], fullmask ? fillv : p[3]);
        float4 o1 = make_float4(fullmask ? fillv : p[4], fullmask ? fillv : p[5],
                                fullmask ? fillv : p[6], fullmask ? fillv : p[7]);
        *(float4*)(arow + c)     = o0;
        *(float4*)(arow + c + 4) = o1;
        bf16x8v pb;
#pragma unroll
        for (int i = 0; i < 8; i++) pb[i] = f2bf(p[i]);
        *(bf16x8v*)((char*)s_lds + byte) = pb;
      } else {
        bf16x8v zz = {0, 0, 0, 0, 0, 0, 0, 0};
        *(bf16x8v*)((char*)s_lds + byte) = zz;
      }
    }
    for (int c = L + j * 8; c < T_; c += 128) {
      float4 f4 = make_float4(fillv, fillv, fillv, fillv);
      *(float4*)(arow + c)     = f4;
      *(float4*)(arow + c + 4) = f4;
    }
  }
  __syncthreads();

  // ---- phase 3b: out_h = P * V (MFMA); one 16x16 tile per wave ----
  {
    int bsel = w >> 2;
    int hd0  = (w & 3) * 16;
    f32x4 acc = {0.f, 0.f, 0.f, 0.f};
    const short* vb = vt + (((size_t)bsel * H_ + h) * HD_ + hd0 + fr) * T_;
    for (int k0 = 0; k0 < Lpad; k0 += 32) {
      int arow = bsel * 16 + fr;
      int byte = (arow * 4096 + (k0 + kq8) * 2) ^ ((arow & 7) << 4);
      bf16x8v pa = *(const bf16x8v*)((char*)s_lds + byte);
      bf16x8v vv = *(const bf16x8v*)(vb + k0 + kq8);
      acc = MFMA16(pa, vv, acc);
    }
#pragma unroll
    for (int r = 0; r < 4; r++) {
      int qrel = (l >> 4) * 4 + r;
      int row = bsel * 16 + qrel;
      int hd = hd0 + fr;
      float val = acc[r];
      if (m_lds[row] <= -0.5e9f)
        val = vsum[((size_t)bsel * H_ + h) * HD_ + hd] * (1.0f / (float)T_);
      outh[(((size_t)bsel * H_ + h) * T_ + q0 + qrel) * HD_ + hd] = f2bf(val);
    }
  }
}

// ---------------------------------------------------------------------------
// Output GEMM: out = out_h(4096x1024 logical) * Wo^T, fp32 output
// ---------------------------------------------------------------------------
__global__ __launch_bounds__(256) void out_gemm(
    const short* __restrict__ Ah, const short* __restrict__ Bw, float* __restrict__ Co)
{
  __shared__ short As[128 * 32];
  __shared__ short Bs[128 * 32];
  const int m0 = blockIdx.x * 128;
  const int n0 = blockIdx.y * 128;
  const int tid = threadIdx.x;
  const int w = tid >> 6, l = tid & 63;
  const int wr = w >> 1, wc = w & 1;
  const int fr = l & 15, kq8 = (l >> 4) * 8;
  const int srow = tid >> 2, scol = (tid & 3) * 8;

  f32x4 acc[4][4] = {};

  for (int k0 = 0; k0 < DM; k0 += 32) {
    __syncthreads();
    int kk = k0 + scol;
    int hh = kk >> 6, hd = kk & 63;
    {
      int m1 = m0 + srow;
      const short* src1 = Ah + (((size_t)(m1 >> 11) * H_ + hh) * T_ + (m1 & (T_ - 1))) * HD_ + hd;
      GLOAD_LDS16(src1, (char*)As + tid * 16);
      int m2 = m0 + 64 + srow;
      const short* src2 = Ah + (((size_t)(m2 >> 11) * H_ + hh) * T_ + (m2 & (T_ - 1))) * HD_ + hd;
      GLOAD_LDS16(src2, (char*)As + 4096 + tid * 16);
    }
    GLOAD_LDS16(Bw + (size_t)(n0 + srow) * DM + kk,      (char*)Bs + tid * 16);
    GLOAD_LDS16(Bw + (size_t)(n0 + 64 + srow) * DM + kk, (char*)Bs + 4096 + tid * 16);
    __syncthreads();
    bf16x8v a[4], b[4];
#pragma unroll
    for (int i = 0; i < 4; i++) a[i] = *(const bf16x8v*)&As[(wr * 64 + i * 16 + fr) * 32 + kq8];
#pragma unroll
    for (int j = 0; j < 4; j++) b[j] = *(const bf16x8v*)&Bs[(wc * 64 + j * 16 + fr) * 32 + kq8];
#pragma unroll
    for (int i = 0; i < 4; i++)
#pragma unroll
      for (int j = 0; j < 4; j++)
        acc[i][j] = MFMA16(a[i], b[j], acc[i][j]);
  }

#pragma unroll
  for (int i = 0; i < 4; i++)
#pragma unroll
    for (int j = 0; j < 4; j++)
#pragma unroll
      for (int r = 0; r < 4; r++) {
        int row = m0 + wr * 64 + i * 16 + (l >> 4) * 4 + r;
        int col = n0 + wc * 64 + j * 16 + fr;
        Co[(size_t)row * DM + col] = acc[i][j][r];
      }
}

// ---------------------------------------------------------------------------
extern "C" void kernel_launch(void* const* d_in, const int* in_sizes, int n_in,
                              void* d_out, int out_size, void* d_ws, size_t ws_size,
                              hipStream_t stream)
{
  const float* x_q  = (const float*)d_in[0];
  const float* x_k  = (const float*)d_in[1];
  const float* x_v  = (const float*)d_in[2];
  const int*   mask = (const int*)d_in[3];
  const int*   causal = (const int*)d_in[4];
  const float* bias = (const float*)d_in[5];
  const float* Wq   = (const float*)d_in[6];
  const float* Wk   = (const float*)d_in[7];
  const float* Wv   = (const float*)d_in[8];
  const float* Wo   = (const float*)d_in[9];

  char* ws = (char*)d_ws;
  const size_t XB = (size_t)B_ * T_ * DM * 2;   // 8 MB
  const size_t WB = (size_t)DM * DM * 2;        // 2 MB
  short* xq_b = (short*)(ws + 0 * XB);
  short* xk_b = (short*)(ws + 1 * XB);
  short* xv_b = (short*)(ws + 2 * XB);
  short* wq_b = (short*)(ws + 3 * XB + 0 * WB);
  short* wk_b = (short*)(ws + 3 * XB + 1 * WB);
  short* wv_b = (short*)(ws + 3 * XB + 2 * WB);
  short* wo_b = (short*)(ws + 3 * XB + 3 * WB);
  short* q_ws  = (short*)(ws + 3 * XB + 4 * WB);
  short* k_ws  = (short*)(ws + 4 * XB + 4 * WB);
  short* vt_ws = (short*)(ws + 5 * XB + 4 * WB);
  short* oh_ws = (short*)(ws + 6 * XB + 4 * WB);
  float* vs_ws = (float*)(ws + 7 * XB + 4 * WB);

  float* out0 = (float*)d_out;
  float* attn = out0 + (size_t)B_ * T_ * DM;

  conv_kernel<<<dim3(4096, 7, 1), 256, 0, stream>>>(
      x_q, x_k, x_v, Wq, Wk, Wv, Wo,
      xq_b, xk_b, xv_b, wq_b, wk_b, wv_b, wo_b);

  proj_gemm<<<dim3(32, 8, 3), 256, 0, stream>>>(
      xq_b, xk_b, xv_b, wq_b, wk_b, wv_b, q_ws, k_ws, vt_ws);

  vsum_kernel<<<dim3(32, 1, 1), 256, 0, stream>>>(vt_ws, vs_ws);

  attn_kernel<<<dim3(T_ / 16, H_, 1), 512, 0, stream>>>(
      q_ws, k_ws, vt_ws, bias, mask, causal, vs_ws, attn, oh_ws);

  out_gemm<<<dim3(32, 8, 1), 256, 0, stream>>>(oh_ws, wo_b, out0);
}

// Round 3
// 463.289 us; speedup vs baseline: 1.1164x; 1.1164x over previous
//
#include <hip/hip_runtime.h>
#include <hip/hip_bf16.h>
#include <hip/hip_fp16.h>

#define B_ 2
#define T_ 2048
#define DM 1024
#define H_ 16
#define HD_ 64

typedef __attribute__((ext_vector_type(8))) short bf16x8v;
typedef __attribute__((ext_vector_type(4))) short short4v;
typedef __attribute__((ext_vector_type(4))) float f32x4;

__device__ __forceinline__ short f2bf(float f){
  unsigned u = __builtin_bit_cast(unsigned, f);
  u += 0x7fffu + ((u >> 16) & 1u);
  return (short)(u >> 16);
}
__device__ __forceinline__ float bf2f(short s){
  unsigned u = ((unsigned)(unsigned short)s) << 16;
  return __builtin_bit_cast(float, u);
}
__device__ __forceinline__ short f2h(float f){
  return __builtin_bit_cast(short, __float2half(f));
}
__device__ __forceinline__ float h2f(short s){
  return __half2float(__builtin_bit_cast(__half, s));
}

#define GLOAD_LDS16(g, l) \
  __builtin_amdgcn_global_load_lds((const __attribute__((address_space(1))) unsigned int*)(g), \
                                   (__attribute__((address_space(3))) unsigned int*)(l), 16, 0, 0)

#define MFMA16(a, b, c) __builtin_amdgcn_mfma_f32_16x16x32_bf16((a), (b), (c), 0, 0, 0)

// ---------------------------------------------------------------------------
// fp32 -> bf16 conversion for 3 activations (4M elems) + 4 weights (1M elems)
// ---------------------------------------------------------------------------
__global__ __launch_bounds__(256) void conv_kernel(
    const float* __restrict__ s0, const float* __restrict__ s1, const float* __restrict__ s2,
    const float* __restrict__ s3, const float* __restrict__ s4, const float* __restrict__ s5,
    const float* __restrict__ s6,
    short* __restrict__ d0, short* __restrict__ d1, short* __restrict__ d2,
    short* __restrict__ d3, short* __restrict__ d4, short* __restrict__ d5,
    short* __restrict__ d6)
{
  int y = blockIdx.y;
  const float* s; short* d; int n;
  switch (y) {
    case 0: s = s0; d = d0; n = B_*T_*DM; break;
    case 1: s = s1; d = d1; n = B_*T_*DM; break;
    case 2: s = s2; d = d2; n = B_*T_*DM; break;
    case 3: s = s3; d = d3; n = DM*DM;   break;
    case 4: s = s4; d = d4; n = DM*DM;   break;
    case 5: s = s5; d = d5; n = DM*DM;   break;
    default: s = s6; d = d6; n = DM*DM;  break;
  }
  int i = (blockIdx.x * 256 + threadIdx.x) * 4;
  if (i >= n) return;
  float4 f = *(const float4*)(s + i);
  short4v o;
  o.x = f2bf(f.x); o.y = f2bf(f.y); o.z = f2bf(f.z); o.w = f2bf(f.w);
  *(short4v*)(d + i) = o;
}

// ---------------------------------------------------------------------------
// Projection GEMM: C = X(4096x1024) * W^T(1024x1024), bf16 MFMA, 128x128 tile.
// z=0: Q (scaled 1/8) -> [b,h,t,hd]; z=1: K -> [b,h,t,hd]; z=2: V -> [b,h,hd,t]
// ---------------------------------------------------------------------------
__global__ __launch_bounds__(256) void proj_gemm(
    const short* __restrict__ xq, const short* __restrict__ xk, const short* __restrict__ xv,
    const short* __restrict__ wq, const short* __restrict__ wk, const short* __restrict__ wv,
    short* __restrict__ qo, short* __restrict__ ko, short* __restrict__ vto)
{
  __shared__ short As[128 * 32];
  __shared__ short Bs[128 * 32];
  const int z = blockIdx.z;
  const short* A  = (z == 0) ? xq : (z == 1) ? xk : xv;
  const short* Bw = (z == 0) ? wq : (z == 1) ? wk : wv;
  const int m0 = blockIdx.x * 128;
  const int n0 = blockIdx.y * 128;
  const int tid = threadIdx.x;
  const int w = tid >> 6, l = tid & 63;
  const int wr = w >> 1, wc = w & 1;
  const int fr = l & 15, kq8 = (l >> 4) * 8;
  const int srow = tid >> 2, scol = (tid & 3) * 8;

  f32x4 acc[4][4] = {};

  for (int k0 = 0; k0 < DM; k0 += 32) {
    __syncthreads();
    GLOAD_LDS16(A  + (size_t)(m0 + srow) * DM + k0 + scol,      (char*)As + tid * 16);
    GLOAD_LDS16(A  + (size_t)(m0 + 64 + srow) * DM + k0 + scol, (char*)As + 4096 + tid * 16);
    GLOAD_LDS16(Bw + (size_t)(n0 + srow) * DM + k0 + scol,      (char*)Bs + tid * 16);
    GLOAD_LDS16(Bw + (size_t)(n0 + 64 + srow) * DM + k0 + scol, (char*)Bs + 4096 + tid * 16);
    __syncthreads();
    bf16x8v a[4], b[4];
#pragma unroll
    for (int i = 0; i < 4; i++) a[i] = *(const bf16x8v*)&As[(wr * 64 + i * 16 + fr) * 32 + kq8];
#pragma unroll
    for (int j = 0; j < 4; j++) b[j] = *(const bf16x8v*)&Bs[(wc * 64 + j * 16 + fr) * 32 + kq8];
#pragma unroll
    for (int i = 0; i < 4; i++)
#pragma unroll
      for (int j = 0; j < 4; j++)
        acc[i][j] = MFMA16(a[i], b[j], acc[i][j]);
  }

  const float scale = (z == 0) ? 0.125f : 1.0f;
  short* dst01 = (z == 0) ? qo : ko;
#pragma unroll
  for (int i = 0; i < 4; i++) {
#pragma unroll
    for (int j = 0; j < 4; j++) {
#pragma unroll
      for (int r = 0; r < 4; r++) {
        int row = m0 + wr * 64 + i * 16 + (l >> 4) * 4 + r;
        int col = n0 + wc * 64 + j * 16 + fr;
        int bb = row >> 11, tt = row & (T_ - 1);
        int hh = col >> 6,  hd = col & (HD_ - 1);
        short v = f2bf(acc[i][j][r] * scale);
        if (z == 2)
          vto[(((size_t)bb * H_ + hh) * HD_ + hd) * T_ + tt] = v;
        else
          dst01[(((size_t)bb * H_ + hh) * T_ + tt) * HD_ + hd] = v;
      }
    }
  }
}

// ---------------------------------------------------------------------------
// Column sums of V (for fully-masked rows): vs[bh*64+hd] = sum_t V[bh][t][hd]
// ---------------------------------------------------------------------------
__global__ __launch_bounds__(256) void vsum_kernel(const short* __restrict__ vt,
                                                   float* __restrict__ vs)
{
  __shared__ float red[256];
  int bh = blockIdx.x;
  int tid = threadIdx.x;
  int hd = tid & 63, part = tid >> 6;
  const short* src = vt + ((size_t)bh * HD_ + hd) * T_ + part * 512;
  float s = 0.f;
  for (int i = 0; i < 512; i += 4) {
    short4v v = *(const short4v*)(src + i);
    s += bf2f(v.x) + bf2f(v.y) + bf2f(v.z) + bf2f(v.w);
  }
  red[tid] = s;
  __syncthreads();
  if (part == 0)
    vs[(size_t)bh * HD_ + hd] = red[hd] + red[64 + hd] + red[128 + hd] + red[192 + hd];
}

// ---------------------------------------------------------------------------
// Attention: one WG per (batch, 8-q-row tile, head). 512 threads.
// LDS: 32KB fp16 score row-block (XOR swizzled) + 2KB mask + 4KB PV partials.
// grid (B, T/8, H) — batch fastest so b0/b1 share bias via L2/LLC.
// ---------------------------------------------------------------------------
__global__ __launch_bounds__(512, 6) void attn_kernel(
    const short* __restrict__ qw, const short* __restrict__ kw, const short* __restrict__ vt,
    const float* __restrict__ bias, const int* __restrict__ mask,
    const int* __restrict__ causal_p, const float* __restrict__ vsum,
    float* __restrict__ attn_out, short* __restrict__ outh)
{
  __shared__ short s_lds[8 * 2048];           // 32 KB fp16 scores -> bf16 p
  __shared__ unsigned char mk_lds[T_];        // 2 KB
  __shared__ float m_lds[8], l_lds[8];
  __shared__ float pv_lds[2][8][64];          // 4 KB PV partial sums

  const int b  = blockIdx.x;
  const int q0 = blockIdx.y * 8;
  const int h  = blockIdx.z;
  const int tid = threadIdx.x;
  const int w = tid >> 6, l = tid & 63;
  const int causal = *causal_p;
  const int L = causal ? (q0 + 8) : T_;
  const int Lpad = (L + 31) & ~31;
  const int fr = l & 15, kq8 = (l >> 4) * 8;

  for (int i = tid; i < T_; i += 512)
    mk_lds[i] = (unsigned char)(mask[b * T_ + i] != 0);
  __syncthreads();

  // ---- phase 1: scores = (Q/8)K^T + bias, masked -> LDS fp16 (swizzled) ----
  {
    bf16x8v qf[2];
#pragma unroll
    for (int ks = 0; ks < 2; ks++)
      qf[ks] = *(const bf16x8v*)&qw[(((size_t)b * H_ + h) * T_ + q0 + (fr & 7)) * HD_ + ks * 32 + kq8];

    for (int nt = 0; nt < 16; ++nt) {
      int k0 = (nt * 8 + w) * 16;            // interleave k-tiles across waves
      if (k0 >= L) break;
      f32x4 acc = {0.f, 0.f, 0.f, 0.f};
      const short* kb = &kw[(((size_t)b * H_ + h) * T_ + k0 + fr) * HD_ + kq8];
      acc = MFMA16(qf[0], *(const bf16x8v*)kb, acc);
      acc = MFMA16(qf[1], *(const bf16x8v*)(kb + 32), acc);
      if ((l >> 4) < 2) {                    // acc rows 0-7 are the valid ones
        int colg = k0 + fr;
        unsigned char mk = mk_lds[colg];
        const float* bp = bias + ((size_t)h * T_ + q0 + (l >> 4) * 4) * T_ + colg;
#pragma unroll
        for (int r = 0; r < 4; r++) {
          int qrel = (l >> 4) * 4 + r;
          float bi = bp[r * T_];
          bool cok = (!causal) || (colg <= q0 + qrel);
          float s = (mk && cok) ? (acc[r] + bi) : -1e9f;
          *(short*)((char*)s_lds + ((qrel * 4096 + colg * 2) ^ ((qrel & 7) << 4))) = f2h(s);
        }
      }
    }
  }
  __syncthreads();

  // ---- phase 2: per-row max and sum(exp) over [0,L); one wave per row ----
  {
    int row = w;
    float mx = -3e38f;
    for (int c = l * 8; c < L; c += 512) {
      int byte = (row * 4096 + c * 2) ^ ((row & 7) << 4);
      bf16x8v v = *(const bf16x8v*)((char*)s_lds + byte);
#pragma unroll
      for (int i = 0; i < 8; i++) mx = fmaxf(mx, h2f(v[i]));
    }
#pragma unroll
    for (int off = 1; off < 64; off <<= 1) mx = fmaxf(mx, __shfl_xor(mx, off));
    float sm = 0.f;
    for (int c = l * 8; c < L; c += 512) {
      int byte = (row * 4096 + c * 2) ^ ((row & 7) << 4);
      bf16x8v v = *(const bf16x8v*)((char*)s_lds + byte);
#pragma unroll
      for (int i = 0; i < 8; i++) sm += __expf(h2f(v[i]) - mx);
    }
#pragma unroll
    for (int off = 1; off < 64; off <<= 1) sm += __shfl_xor(sm, off);
    if (l == 0) { m_lds[row] = mx; l_lds[row] = sm; }
  }
  __syncthreads();

  // ---- phase 3a: p = exp(s-m)/l; NT-write attn fp32; p (bf16) -> LDS ----
  {
    int row = w;
    int qg = q0 + row;
    float mx = m_lds[row];
    bool fullmask = (mx <= -0.5e9f);
    float inv = fullmask ? 0.f : (1.0f / l_lds[row]);
    float fillv = fullmask ? (1.0f / (float)T_) : 0.f;
    float* arow = attn_out + (((size_t)b * H_ + h) * T_ + qg) * T_;
    for (int c = l * 8; c < Lpad; c += 512) {
      int byte = (row * 4096 + c * 2) ^ ((row & 7) << 4);
      if (c < L) {
        bf16x8v v = *(const bf16x8v*)((char*)s_lds + byte);
        float p[8];
#pragma unroll
        for (int i = 0; i < 8; i++)
          p[i] = fullmask ? 0.f : __expf(h2f(v[i]) - mx) * inv;
        f32x4 o0 = {fullmask ? fillv : p[0], fullmask ? fillv : p[1],
                    fullmask ? fillv : p[2], fullmask ? fillv : p[3]};
        f32x4 o1 = {fullmask ? fillv : p[4], fullmask ? fillv : p[5],
                    fullmask ? fillv : p[6], fullmask ? fillv : p[7]};
        __builtin_nontemporal_store(o0, (f32x4*)(arow + c));
        __builtin_nontemporal_store(o1, (f32x4*)(arow + c + 4));
        bf16x8v pb;
#pragma unroll
        for (int i = 0; i < 8; i++) pb[i] = f2bf(p[i]);
        *(bf16x8v*)((char*)s_lds + byte) = pb;
      } else {
        bf16x8v zz = {0, 0, 0, 0, 0, 0, 0, 0};
        *(bf16x8v*)((char*)s_lds + byte) = zz;
      }
    }
    f32x4 f4 = {fillv, fillv, fillv, fillv};
    for (int c = L + l * 8; c < T_; c += 512) {
      __builtin_nontemporal_store(f4, (f32x4*)(arow + c));
      __builtin_nontemporal_store(f4, (f32x4*)(arow + c + 4));
    }
  }
  __syncthreads();

  // ---- phase 3b: out_h = P * V (MFMA); wave w: hd tile (w&3), k-half (w>>2) ----
  {
    int half = w >> 2;
    int hd0  = (w & 3) * 16;
    int split = (Lpad / 2) & ~31;
    int kbeg = half ? split : 0;
    int kend = half ? Lpad  : split;
    f32x4 acc = {0.f, 0.f, 0.f, 0.f};
    const short* vb = vt + (((size_t)b * H_ + h) * HD_ + hd0 + fr) * T_;
    int arow = fr & 7;
    for (int k0 = kbeg; k0 < kend; k0 += 32) {
      int byte = (arow * 4096 + (k0 + kq8) * 2) ^ ((arow & 7) << 4);
      bf16x8v pa = *(const bf16x8v*)((char*)s_lds + byte);
      bf16x8v vv = *(const bf16x8v*)(vb + k0 + kq8);
      acc = MFMA16(pa, vv, acc);
    }
    if ((l >> 4) < 2) {
#pragma unroll
      for (int r = 0; r < 4; r++)
        pv_lds[half][(l >> 4) * 4 + r][hd0 + fr] = acc[r];
    }
  }
  __syncthreads();
  {
    int row = tid >> 6, hd = tid & 63;
    float val = pv_lds[0][row][hd] + pv_lds[1][row][hd];
    if (m_lds[row] <= -0.5e9f)
      val = vsum[((size_t)b * H_ + h) * HD_ + hd] * (1.0f / (float)T_);
    outh[(((size_t)b * H_ + h) * T_ + q0 + row) * HD_ + hd] = f2bf(val);
  }
}

// ---------------------------------------------------------------------------
// Output GEMM: out = out_h(4096x1024 logical) * Wo^T, fp32 output
// ---------------------------------------------------------------------------
__global__ __launch_bounds__(256) void out_gemm(
    const short* __restrict__ Ah, const short* __restrict__ Bw, float* __restrict__ Co)
{
  __shared__ short As[128 * 32];
  __shared__ short Bs[128 * 32];
  const int m0 = blockIdx.x * 128;
  const int n0 = blockIdx.y * 128;
  const int tid = threadIdx.x;
  const int w = tid >> 6, l = tid & 63;
  const int wr = w >> 1, wc = w & 1;
  const int fr = l & 15, kq8 = (l >> 4) * 8;
  const int srow = tid >> 2, scol = (tid & 3) * 8;

  f32x4 acc[4][4] = {};

  for (int k0 = 0; k0 < DM; k0 += 32) {
    __syncthreads();
    int kk = k0 + scol;
    int hh = kk >> 6, hd = kk & 63;
    {
      int m1 = m0 + srow;
      const short* src1 = Ah + (((size_t)(m1 >> 11) * H_ + hh) * T_ + (m1 & (T_ - 1))) * HD_ + hd;
      GLOAD_LDS16(src1, (char*)As + tid * 16);
      int m2 = m0 + 64 + srow;
      const short* src2 = Ah + (((size_t)(m2 >> 11) * H_ + hh) * T_ + (m2 & (T_ - 1))) * HD_ + hd;
      GLOAD_LDS16(src2, (char*)As + 4096 + tid * 16);
    }
    GLOAD_LDS16(Bw + (size_t)(n0 + srow) * DM + kk,      (char*)Bs + tid * 16);
    GLOAD_LDS16(Bw + (size_t)(n0 + 64 + srow) * DM + kk, (char*)Bs + 4096 + tid * 16);
    __syncthreads();
    bf16x8v a[4], b[4];
#pragma unroll
    for (int i = 0; i < 4; i++) a[i] = *(const bf16x8v*)&As[(wr * 64 + i * 16 + fr) * 32 + kq8];
#pragma unroll
    for (int j = 0; j < 4; j++) b[j] = *(const bf16x8v*)&Bs[(wc * 64 + j * 16 + fr) * 32 + kq8];
#pragma unroll
    for (int i = 0; i < 4; i++)
#pragma unroll
      for (int j = 0; j < 4; j++)
        acc[i][j] = MFMA16(a[i], b[j], acc[i][j]);
  }

#pragma unroll
  for (int i = 0; i < 4; i++)
#pragma unroll
    for (int j = 0; j < 4; j++)
#pragma unroll
      for (int r = 0; r < 4; r++) {
        int row = m0 + wr * 64 + i * 16 + (l >> 4) * 4 + r;
        int col = n0 + wc * 64 + j * 16 + fr;
        Co[(size_t)row * DM + col] = acc[i][j][r];
      }
}

// ---------------------------------------------------------------------------
extern "C" void kernel_launch(void* const* d_in, const int* in_sizes, int n_in,
                              void* d_out, int out_size, void* d_ws, size_t ws_size,
                              hipStream_t stream)
{
  const float* x_q  = (const float*)d_in[0];
  const float* x_k  = (const float*)d_in[1];
  const float* x_v  = (const float*)d_in[2];
  const int*   mask = (const int*)d_in[3];
  const int*   causal = (const int*)d_in[4];
  const float* bias = (const float*)d_in[5];
  const float* Wq   = (const float*)d_in[6];
  const float* Wk   = (const float*)d_in[7];
  const float* Wv   = (const float*)d_in[8];
  const float* Wo   = (const float*)d_in[9];

  char* ws = (char*)d_ws;
  const size_t XB = (size_t)B_ * T_ * DM * 2;   // 8 MB
  const size_t WB = (size_t)DM * DM * 2;        // 2 MB
  short* xq_b = (short*)(ws + 0 * XB);
  short* xk_b = (short*)(ws + 1 * XB);
  short* xv_b = (short*)(ws + 2 * XB);
  short* wq_b = (short*)(ws + 3 * XB + 0 * WB);
  short* wk_b = (short*)(ws + 3 * XB + 1 * WB);
  short* wv_b = (short*)(ws + 3 * XB + 2 * WB);
  short* wo_b = (short*)(ws + 3 * XB + 3 * WB);
  short* q_ws  = (short*)(ws + 3 * XB + 4 * WB);
  short* k_ws  = (short*)(ws + 4 * XB + 4 * WB);
  short* vt_ws = (short*)(ws + 5 * XB + 4 * WB);
  short* oh_ws = (short*)(ws + 6 * XB + 4 * WB);
  float* vs_ws = (float*)(ws + 7 * XB + 4 * WB);

  float* out0 = (float*)d_out;
  float* attn = out0 + (size_t)B_ * T_ * DM;

  conv_kernel<<<dim3(4096, 7, 1), 256, 0, stream>>>(
      x_q, x_k, x_v, Wq, Wk, Wv, Wo,
      xq_b, xk_b, xv_b, wq_b, wk_b, wv_b, wo_b);

  proj_gemm<<<dim3(32, 8, 3), 256, 0, stream>>>(
      xq_b, xk_b, xv_b, wq_b, wk_b, wv_b, q_ws, k_ws, vt_ws);

  vsum_kernel<<<dim3(32, 1, 1), 256, 0, stream>>>(vt_ws, vs_ws);

  attn_kernel<<<dim3(B_, T_ / 8, H_), 512, 0, stream>>>(
      q_ws, k_ws, vt_ws, bias, mask, causal, vs_ws, attn, oh_ws);

  out_gemm<<<dim3(32, 8, 1), 256, 0, stream>>>(oh_ws, wo_b, out0);
}